// Round 8
// baseline (388.949 us; speedup 1.0000x reference)
//
#include <hip/hip_runtime.h>

#define Bb 8
#define Nn 20000
#define Cc 128
#define Kk 64
#define Ee 320000

#define WAVES_PER_BLOCK 4
#define NSEG 512        // segments per batch (pooled: 1024 blocks * 4 waves / 8 batches)
#define SEGCAP 640      // ceil(5000/512)=10 groups/seg * 64 edges = 640 max valid

typedef __attribute__((ext_vector_type(8))) short bf16x8;
typedef __attribute__((ext_vector_type(16))) float f32x16;

__device__ __forceinline__ unsigned short f2bf(float f) {
    unsigned int u = __float_as_uint(f);
    u += 0x7FFFu + ((u >> 16) & 1u);          // round-to-nearest-even
    return (unsigned short)(u >> 16);
}

// ---------------------------------------------------------------------------
// Kernel 1: S = softmax(relu(x@W1+b1)@W2+b2) * m   (MFMA, unchanged from R6)
// ---------------------------------------------------------------------------
__global__ __launch_bounds__(256) void k_compute_S(
    const float* __restrict__ x, const int* __restrict__ mask,
    const float* __restrict__ W1, const float* __restrict__ b1,
    const float* __restrict__ W2, const float* __restrict__ b2,
    float* __restrict__ S)
{
    __shared__ unsigned short W1A[8192];
    __shared__ unsigned short W2A[4096];
    __shared__ float b1s[Kk];
    __shared__ float b2s[Kk];

    const int tid = threadIdx.x;

    for (int idx = tid; idx < 8192; idx += 256) {
        const int j  = idx & 7;
        const int ln = (idx >> 3) & 63;
        const int t  = idx >> 9;
        const int kh = t & 1;
        const int cs = t >> 1;
        W1A[idx] = f2bf(W1[(cs * 16 + (ln >> 5) * 8 + j) * Kk + kh * 32 + (ln & 31)]);
    }
    for (int idx = tid; idx < 4096; idx += 256) {
        const int j  = idx & 7;
        const int ln = (idx >> 3) & 63;
        const int t  = idx >> 9;
        const int lh = t & 1;
        const int ks = t >> 1;
        W2A[idx] = f2bf(W2[(ks * 16 + (ln >> 5) * 8 + j) * Kk + lh * 32 + (ln & 31)]);
    }
    if (tid < Kk) { b1s[tid] = b1[tid]; b2s[tid] = b2[tid]; }
    __syncthreads();

    const int lane = tid & 63;
    const int wid  = tid >> 6;
    const int hsel = lane >> 5;
    const int m32  = lane & 31;

    const int wc = blockIdx.x * WAVES_PER_BLOCK + wid;
    const int chunksPerBatch = Nn / 32;
    const int b  = wc / chunksPerBatch;
    const int n0 = (wc % chunksPerBatch) * 32;
    const int nd = n0 + m32;

    const float* xrow = x + ((size_t)b * Nn + nd) * Cc;
    f32x16 accA = 0.f, accB = 0.f;
    #pragma unroll
    for (int cs = 0; cs < 8; ++cs) {
        const float4 f0 = *(const float4*)&xrow[cs * 16 + hsel * 8];
        const float4 f1 = *(const float4*)&xrow[cs * 16 + hsel * 8 + 4];
        bf16x8 xa;
        xa[0] = (short)f2bf(f0.x); xa[1] = (short)f2bf(f0.y);
        xa[2] = (short)f2bf(f0.z); xa[3] = (short)f2bf(f0.w);
        xa[4] = (short)f2bf(f1.x); xa[5] = (short)f2bf(f1.y);
        xa[6] = (short)f2bf(f1.z); xa[7] = (short)f2bf(f1.w);
        const bf16x8 w1h0 = *(const bf16x8*)&W1A[((cs * 2 + 0) * 64 + lane) * 8];
        const bf16x8 w1h1 = *(const bf16x8*)&W1A[((cs * 2 + 1) * 64 + lane) * 8];
        accA = __builtin_amdgcn_mfma_f32_32x32x16_bf16(w1h0, xa, accA, 0, 0, 0);
        accB = __builtin_amdgcn_mfma_f32_32x32x16_bf16(w1h1, xa, accB, 0, 0, 0);
    }

    f32x16 accS0 = 0.f, accS1 = 0.f;

#define EXTRACT_GEMM2(KS, ACC)                                                 \
    {                                                                          \
        bf16x8 hf;                                                             \
        _Pragma("unroll")                                                      \
        for (int jj = 0; jj < 4; ++jj) {                                       \
            const int c0 = jj + 8 * ((KS) & 1);                                \
            const float own  = hsel ? (ACC)[c0 + 4] : (ACC)[c0];               \
            const float send = hsel ? (ACC)[c0]     : (ACC)[c0 + 4];           \
            const float sw   = __shfl_xor(send, 32);                           \
            const float vlo  = hsel ? sw  : own;                               \
            const float vhi  = hsel ? own : sw;                                \
            const int klo = (KS) * 16 + 8 * hsel + jj;                         \
            hf[jj]     = (short)f2bf(fmaxf(vlo + b1s[klo], 0.f));              \
            hf[jj + 4] = (short)f2bf(fmaxf(vhi + b1s[klo + 4], 0.f));          \
        }                                                                      \
        const bf16x8 w2l0 = *(const bf16x8*)&W2A[(((KS) * 2 + 0) * 64 + lane) * 8]; \
        const bf16x8 w2l1 = *(const bf16x8*)&W2A[(((KS) * 2 + 1) * 64 + lane) * 8]; \
        accS0 = __builtin_amdgcn_mfma_f32_32x32x16_bf16(w2l0, hf, accS0, 0, 0, 0); \
        accS1 = __builtin_amdgcn_mfma_f32_32x32x16_bf16(w2l1, hf, accS1, 0, 0, 0); \
    }

    EXTRACT_GEMM2(0, accA)
    EXTRACT_GEMM2(1, accA)
    EXTRACT_GEMM2(2, accB)
    EXTRACT_GEMM2(3, accB)
#undef EXTRACT_GEMM2

    float z0[16], z1[16];
    float mm = -1e30f;
    #pragma unroll
    for (int r = 0; r < 16; ++r) {
        const int l = (r & 3) + 8 * (r >> 2) + 4 * hsel;
        z0[r] = accS0[r] + b2s[l];
        z1[r] = accS1[r] + b2s[l + 32];
        mm = fmaxf(mm, fmaxf(z0[r], z1[r]));
    }
    mm = fmaxf(mm, __shfl_xor(mm, 32));
    float ssum = 0.f;
    #pragma unroll
    for (int r = 0; r < 16; ++r) {
        z0[r] = __expf(z0[r] - mm);
        z1[r] = __expf(z1[r] - mm);
        ssum += z0[r] + z1[r];
    }
    ssum += __shfl_xor(ssum, 32);
    const int   mv = mask[(size_t)b * Nn + nd];
    const float rs = (mv > 0) ? (1.f / ssum) : 0.f;

    float* Srow = S + ((size_t)b * Nn + nd) * Kk;
    #pragma unroll
    for (int g = 0; g < 4; ++g) {
        float4 s0, s1;
        s0.x = z0[4 * g + 0] * rs; s0.y = z0[4 * g + 1] * rs;
        s0.z = z0[4 * g + 2] * rs; s0.w = z0[4 * g + 3] * rs;
        s1.x = z1[4 * g + 0] * rs; s1.y = z1[4 * g + 1] * rs;
        s1.z = z1[4 * g + 2] * rs; s1.w = z1[4 * g + 3] * rs;
        *(float4*)&Srow[8 * g + 4 * hsel]      = s0;
        *(float4*)&Srow[8 * g + 4 * hsel + 32] = s1;
    }
}

// ---------------------------------------------------------------------------
// Kernel 2: pmask (unchanged)
// ---------------------------------------------------------------------------
__global__ __launch_bounds__(256) void k_pmask(const int* __restrict__ mask,
                                               float* __restrict__ pmask)
{
    __shared__ int s_any;
    if (threadIdx.x == 0) s_any = 0;
    __syncthreads();
    const int b = blockIdx.x;
    int any = 0;
    for (int i = threadIdx.x; i < Nn; i += blockDim.x)
        any |= (mask[(size_t)b * Nn + i] > 0) ? 1 : 0;
    if (any) atomicOr(&s_any, 1);
    __syncthreads();
    if (threadIdx.x < Kk)
        pmask[(size_t)b * Kk + threadIdx.x] = s_any ? 1.f : 0.f;
}

// ---------------------------------------------------------------------------
// Kernel 3a (new): deterministic per-segment edge compaction, no atomics.
// Wave (b,seg) compacts its groups {seg, seg+NSEG, ...} into ed[b][seg][.]
// ---------------------------------------------------------------------------
__global__ __launch_bounds__(256) void k_compact(
    const int* __restrict__ ei, const int* __restrict__ mask,
    int* __restrict__ ed, int* __restrict__ cnt)
{
    const int lane = threadIdx.x & 63;
    const int wid  = threadIdx.x >> 6;
    const int b    = blockIdx.x & 7;
    const int seg  = (blockIdx.x >> 3) * 4 + wid;   // 0..NSEG-1
    const int groupsPerBatch = Ee / 64;             // 5000
    const size_t eib = (size_t)b * 2 * Ee;
    const int* mb = mask + (size_t)b * Nn;
    int* eds = ed + ((size_t)b * NSEG + seg) * SEGCAP;

    int run = 0;
    for (int g = seg; g < groupsPerBatch; g += NSEG) {
        const int e0 = g * 64;
        const int u = ei[eib + e0 + lane];
        const int v = ei[eib + Ee + e0 + lane];
        const bool valid = (mb[u] > 0) && (mb[v] > 0);
        const unsigned long long mk = __ballot(valid);
        const int myoff = __popcll(mk & ((1ull << lane) - 1ull));
        if (valid) eds[run + myoff] = e0 + lane;
        run += (int)__popcll(mk);
    }
    if (lane == 0) cnt[b * NSEG + seg] = run;
}

// ---------------------------------------------------------------------------
// Kernel 3b (v4): pooled[b,k,l] = sum_e w_e * S[b,v_e,k] * S[b,u_e,l]
// Each wave consumes its own dense segment. Per 16-edge chunk, fragment
// elements gathered DIRECTLY: lane holds A[m=lane&31][e=(lane>>5)*8+j] =
// w*S[v_e][m] etc. -> per j: 4 uniform loads + 4 coalesced 2x128B gathers,
// zero shfl / LDS / waitcnt in the hot loop. Epilogue: partial tile to ws
// (reduced by k_reduce) or atomic fallback if ws too small.
// ---------------------------------------------------------------------------
template<bool USE_PT>
__global__ __launch_bounds__(256) void k_pooled_edges(
    const int* __restrict__ ei, const float* __restrict__ ew,
    const float* __restrict__ S, const int* __restrict__ ed,
    const int* __restrict__ cnt, float* __restrict__ out)  // pt or pooled
{
    __shared__ float tile[Kk * Kk];                 // 16 KB
    const int tid  = threadIdx.x;
    const int lane = tid & 63;
    const int wid  = tid >> 6;
    const int hsel = lane >> 5;
    const int m32  = lane & 31;

    for (int i = tid; i < Kk * Kk; i += 256) tile[i] = 0.f;
    __syncthreads();

    const int b   = blockIdx.x & 7;                 // XCD-pinned batch
    const int seg = (blockIdx.x >> 3) * 4 + wid;    // 0..NSEG-1
    const size_t eib = (size_t)b * 2 * Ee;
    const float* ewb = ew + (size_t)b * Ee;
    const float* Sb  = S + (size_t)b * Nn * Kk;
    const int* eds = ed + ((size_t)b * NSEG + seg) * SEGCAP;
    const int nc = cnt[b * NSEG + seg];

    f32x16 acc00 = 0.f, acc01 = 0.f, acc10 = 0.f, acc11 = 0.f;

    for (int c0 = 0; c0 < nc; c0 += 16) {
        bf16x8 a0, a1, b0, b1;
        #pragma unroll
        for (int j = 0; j < 8; ++j) {
            const int sidx = c0 + hsel * 8 + j;     // uniform per half-wave
            const bool ok = sidx < nc;
            const int e  = eds[ok ? sidx : 0];
            const int uu = ei[eib + e];
            const int vv = ei[eib + Ee + e];
            const float ww = ok ? ewb[e] : 0.f;
            const float sv0 = Sb[(size_t)vv * Kk + m32];        // 2x128B segs
            const float sv1 = Sb[(size_t)vv * Kk + 32 + m32];
            const float su0 = Sb[(size_t)uu * Kk + m32];
            const float su1 = Sb[(size_t)uu * Kk + 32 + m32];
            a0[j] = (short)f2bf(ww * sv0);
            a1[j] = (short)f2bf(ww * sv1);
            b0[j] = (short)f2bf(su0);
            b1[j] = (short)f2bf(su1);
        }
        acc00 = __builtin_amdgcn_mfma_f32_32x32x16_bf16(a0, b0, acc00, 0, 0, 0);
        acc01 = __builtin_amdgcn_mfma_f32_32x32x16_bf16(a0, b1, acc01, 0, 0, 0);
        acc10 = __builtin_amdgcn_mfma_f32_32x32x16_bf16(a1, b0, acc10, 0, 0, 0);
        acc11 = __builtin_amdgcn_mfma_f32_32x32x16_bf16(a1, b1, acc11, 0, 0, 0);
    }

    // block-reduce 4 waves into LDS tile (verified 32x32 C/D mapping)
    const int rbase = 4 * (lane >> 5);
    const int col   = lane & 31;
    #pragma unroll
    for (int r = 0; r < 16; ++r) {
        const int row = (r & 3) + 8 * (r >> 2) + rbase;
        atomicAdd(&tile[row * Kk + col],              acc00[r]);
        atomicAdd(&tile[row * Kk + 32 + col],         acc01[r]);
        atomicAdd(&tile[(32 + row) * Kk + col],       acc10[r]);
        atomicAdd(&tile[(32 + row) * Kk + 32 + col],  acc11[r]);
    }
    __syncthreads();

    if (USE_PT) {
        float* pt = out + (size_t)blockIdx.x * (Kk * Kk);
        for (int i = tid; i < Kk * Kk; i += 256) pt[i] = tile[i];
    } else {
        float* pb = out + (size_t)b * Kk * Kk;
        for (int i = tid; i < Kk * Kk; i += 256) atomicAdd(&pb[i], tile[i]);
    }
}

// ---------------------------------------------------------------------------
// Kernel 3c: sum 128 partial tiles per batch -> pooled
// ---------------------------------------------------------------------------
__global__ __launch_bounds__(256) void k_reduce_pooled(
    const float* __restrict__ pt, float* __restrict__ pooled)
{
    const int b   = blockIdx.x;
    const int tid = threadIdx.x;
    for (int i = tid; i < Kk * Kk; i += 256) {
        float s = 0.f;
        #pragma unroll 4
        for (int slot = 0; slot < 128; ++slot)
            s += pt[(size_t)(slot * 8 + b) * (Kk * Kk) + i];
        pooled[(size_t)b * Kk * Kk + i] = s;
    }
}

// ---------------------------------------------------------------------------
// Kernel 4: pfeat (MFMA, unchanged from R5)
// ---------------------------------------------------------------------------
__global__ __launch_bounds__(256) void k_pfeat(
    const float* __restrict__ x, const float* __restrict__ S,
    float* __restrict__ pfeat)
{
    const int tid  = threadIdx.x;
    const int lane = tid & 63;
    const int wid  = tid >> 6;
    const int b    = blockIdx.x & 7;
    const int slot = blockIdx.x >> 3;
    const int bpb  = gridDim.x >> 3;

    const float* xb  = x + (size_t)b * Nn * Cc;
    const float* Sbp = S + (size_t)b * Nn * Kk;

    const int nodeoff = (lane >> 5) * 8;
    const int kc      = lane & 31;
    const int c       = wid * 32 + kc;

    f32x16 acc0 = 0.f, acc1 = 0.f;

    const int chunks = Nn / 16;
    for (int ch = slot; ch < chunks; ch += bpb) {
        const int nb = ch * 16 + nodeoff;
        float a0f[8], a1f[8], bff[8];
        #pragma unroll
        for (int j = 0; j < 8; ++j) {
            const size_t n = (size_t)(nb + j);
            a0f[j] = Sbp[n * Kk + kc];
            a1f[j] = Sbp[n * Kk + 32 + kc];
            bff[j] = xb[n * Cc + c];
        }
        bf16x8 a0, a1, bbf;
        #pragma unroll
        for (int j = 0; j < 8; ++j) {
            a0[j]  = (short)f2bf(a0f[j]);
            a1[j]  = (short)f2bf(a1f[j]);
            bbf[j] = (short)f2bf(bff[j]);
        }
        acc0 = __builtin_amdgcn_mfma_f32_32x32x16_bf16(a0, bbf, acc0, 0, 0, 0);
        acc1 = __builtin_amdgcn_mfma_f32_32x32x16_bf16(a1, bbf, acc1, 0, 0, 0);
    }

    float* pf = pfeat + (size_t)b * Kk * Cc;
    const int colc  = wid * 32 + (lane & 31);
    const int rbase = 4 * (lane >> 5);
    #pragma unroll
    for (int r = 0; r < 16; ++r) {
        const int row = (r & 3) + 8 * (r >> 2) + rbase;
        atomicAdd(&pf[row * Cc + colc],        acc0[r]);
        atomicAdd(&pf[(32 + row) * Cc + colc], acc1[r]);
    }
}

// ---------------------------------------------------------------------------
extern "C" void kernel_launch(void* const* d_in, const int* in_sizes, int n_in,
                              void* d_out, int out_size, void* d_ws, size_t ws_size,
                              hipStream_t stream)
{
    const float* x    = (const float*)d_in[0];
    const int*   ei   = (const int*)d_in[1];     // int64 ref -> int32 on device
    const float* ew   = (const float*)d_in[2];
    const int*   mask = (const int*)d_in[3];
    const float* W1   = (const float*)d_in[4];
    const float* b1   = (const float*)d_in[5];
    const float* W2   = (const float*)d_in[6];
    const float* b2   = (const float*)d_in[7];

    float* out    = (float*)d_out;
    float* pfeat  = out;
    float* pooled = out + (size_t)Bb * Kk * Cc;
    float* pmask  = out + (size_t)Bb * Kk * Cc + (size_t)Bb * Kk * Kk;

    // workspace layout
    float* S   = (float*)d_ws;                                  // 40.96 MB
    int*   ed  = (int*)(S + (size_t)Bb * Nn * Kk);              // 10.49 MB
    int*   cnt = ed + (size_t)Bb * NSEG * SEGCAP;               // 16 KB
    float* pt  = (float*)(cnt + Bb * NSEG);                     // 16.78 MB
    const size_t needed = (size_t)((char*)(pt + (size_t)1024 * Kk * Kk) - (char*)d_ws);
    const bool use_pt = ws_size >= needed;

    hipMemsetAsync(d_out, 0, sizeof(float) * (size_t)out_size, stream);

    k_compute_S<<<1250, 256, 0, stream>>>(x, mask, W1, b1, W2, b2, S);
    k_pmask<<<Bb, 256, 0, stream>>>(mask, pmask);
    k_compact<<<1024, 256, 0, stream>>>(ei, mask, ed, cnt);
    if (use_pt) {
        k_pooled_edges<true><<<1024, 256, 0, stream>>>(ei, ew, S, ed, cnt, pt);
        k_reduce_pooled<<<Bb, 256, 0, stream>>>(pt, pooled);
    } else {
        k_pooled_edges<false><<<1024, 256, 0, stream>>>(ei, ew, S, ed, cnt, pooled);
    }
    k_pfeat<<<512, 256, 0, stream>>>(x, S, pfeat);
}

// Round 9
// 194.040 us; speedup vs baseline: 2.0045x; 2.0045x over previous
//
#include <hip/hip_runtime.h>

#define Bb 8
#define Nn 20000
#define Cc 128
#define Kk 64
#define Ee 320000

#define WAVES_PER_BLOCK 4
#define NSEG 256        // segments per batch (pooled: 512 blocks * 4 waves / 8 batches)
#define SEGCAP 1280     // hard max: ceil(5000/256)=20 groups * 64 edges

typedef __attribute__((ext_vector_type(8))) short bf16x8;
typedef __attribute__((ext_vector_type(16))) float f32x16;

__device__ __forceinline__ unsigned short f2bf(float f) {
    unsigned int u = __float_as_uint(f);
    u += 0x7FFFu + ((u >> 16) & 1u);          // round-to-nearest-even
    return (unsigned short)(u >> 16);
}

// ---------------------------------------------------------------------------
// Kernel 1: S = softmax(relu(x@W1+b1)@W2+b2) * m   (MFMA, unchanged from R6)
// ---------------------------------------------------------------------------
__global__ __launch_bounds__(256) void k_compute_S(
    const float* __restrict__ x, const int* __restrict__ mask,
    const float* __restrict__ W1, const float* __restrict__ b1,
    const float* __restrict__ W2, const float* __restrict__ b2,
    float* __restrict__ S)
{
    __shared__ unsigned short W1A[8192];
    __shared__ unsigned short W2A[4096];
    __shared__ float b1s[Kk];
    __shared__ float b2s[Kk];

    const int tid = threadIdx.x;

    for (int idx = tid; idx < 8192; idx += 256) {
        const int j  = idx & 7;
        const int ln = (idx >> 3) & 63;
        const int t  = idx >> 9;
        const int kh = t & 1;
        const int cs = t >> 1;
        W1A[idx] = f2bf(W1[(cs * 16 + (ln >> 5) * 8 + j) * Kk + kh * 32 + (ln & 31)]);
    }
    for (int idx = tid; idx < 4096; idx += 256) {
        const int j  = idx & 7;
        const int ln = (idx >> 3) & 63;
        const int t  = idx >> 9;
        const int lh = t & 1;
        const int ks = t >> 1;
        W2A[idx] = f2bf(W2[(ks * 16 + (ln >> 5) * 8 + j) * Kk + lh * 32 + (ln & 31)]);
    }
    if (tid < Kk) { b1s[tid] = b1[tid]; b2s[tid] = b2[tid]; }
    __syncthreads();

    const int lane = tid & 63;
    const int wid  = tid >> 6;
    const int hsel = lane >> 5;
    const int m32  = lane & 31;

    const int wc = blockIdx.x * WAVES_PER_BLOCK + wid;
    const int chunksPerBatch = Nn / 32;
    const int b  = wc / chunksPerBatch;
    const int n0 = (wc % chunksPerBatch) * 32;
    const int nd = n0 + m32;

    const float* xrow = x + ((size_t)b * Nn + nd) * Cc;
    f32x16 accA = 0.f, accB = 0.f;
    #pragma unroll
    for (int cs = 0; cs < 8; ++cs) {
        const float4 f0 = *(const float4*)&xrow[cs * 16 + hsel * 8];
        const float4 f1 = *(const float4*)&xrow[cs * 16 + hsel * 8 + 4];
        bf16x8 xa;
        xa[0] = (short)f2bf(f0.x); xa[1] = (short)f2bf(f0.y);
        xa[2] = (short)f2bf(f0.z); xa[3] = (short)f2bf(f0.w);
        xa[4] = (short)f2bf(f1.x); xa[5] = (short)f2bf(f1.y);
        xa[6] = (short)f2bf(f1.z); xa[7] = (short)f2bf(f1.w);
        const bf16x8 w1h0 = *(const bf16x8*)&W1A[((cs * 2 + 0) * 64 + lane) * 8];
        const bf16x8 w1h1 = *(const bf16x8*)&W1A[((cs * 2 + 1) * 64 + lane) * 8];
        accA = __builtin_amdgcn_mfma_f32_32x32x16_bf16(w1h0, xa, accA, 0, 0, 0);
        accB = __builtin_amdgcn_mfma_f32_32x32x16_bf16(w1h1, xa, accB, 0, 0, 0);
    }

    f32x16 accS0 = 0.f, accS1 = 0.f;

#define EXTRACT_GEMM2(KS, ACC)                                                 \
    {                                                                          \
        bf16x8 hf;                                                             \
        _Pragma("unroll")                                                      \
        for (int jj = 0; jj < 4; ++jj) {                                       \
            const int c0 = jj + 8 * ((KS) & 1);                                \
            const float own  = hsel ? (ACC)[c0 + 4] : (ACC)[c0];               \
            const float send = hsel ? (ACC)[c0]     : (ACC)[c0 + 4];           \
            const float sw   = __shfl_xor(send, 32);                           \
            const float vlo  = hsel ? sw  : own;                               \
            const float vhi  = hsel ? own : sw;                                \
            const int klo = (KS) * 16 + 8 * hsel + jj;                         \
            hf[jj]     = (short)f2bf(fmaxf(vlo + b1s[klo], 0.f));              \
            hf[jj + 4] = (short)f2bf(fmaxf(vhi + b1s[klo + 4], 0.f));          \
        }                                                                      \
        const bf16x8 w2l0 = *(const bf16x8*)&W2A[(((KS) * 2 + 0) * 64 + lane) * 8]; \
        const bf16x8 w2l1 = *(const bf16x8*)&W2A[(((KS) * 2 + 1) * 64 + lane) * 8]; \
        accS0 = __builtin_amdgcn_mfma_f32_32x32x16_bf16(w2l0, hf, accS0, 0, 0, 0); \
        accS1 = __builtin_amdgcn_mfma_f32_32x32x16_bf16(w2l1, hf, accS1, 0, 0, 0); \
    }

    EXTRACT_GEMM2(0, accA)
    EXTRACT_GEMM2(1, accA)
    EXTRACT_GEMM2(2, accB)
    EXTRACT_GEMM2(3, accB)
#undef EXTRACT_GEMM2

    float z0[16], z1[16];
    float mm = -1e30f;
    #pragma unroll
    for (int r = 0; r < 16; ++r) {
        const int l = (r & 3) + 8 * (r >> 2) + 4 * hsel;
        z0[r] = accS0[r] + b2s[l];
        z1[r] = accS1[r] + b2s[l + 32];
        mm = fmaxf(mm, fmaxf(z0[r], z1[r]));
    }
    mm = fmaxf(mm, __shfl_xor(mm, 32));
    float ssum = 0.f;
    #pragma unroll
    for (int r = 0; r < 16; ++r) {
        z0[r] = __expf(z0[r] - mm);
        z1[r] = __expf(z1[r] - mm);
        ssum += z0[r] + z1[r];
    }
    ssum += __shfl_xor(ssum, 32);
    const int   mv = mask[(size_t)b * Nn + nd];
    const float rs = (mv > 0) ? (1.f / ssum) : 0.f;

    float* Srow = S + ((size_t)b * Nn + nd) * Kk;
    #pragma unroll
    for (int g = 0; g < 4; ++g) {
        float4 s0, s1;
        s0.x = z0[4 * g + 0] * rs; s0.y = z0[4 * g + 1] * rs;
        s0.z = z0[4 * g + 2] * rs; s0.w = z0[4 * g + 3] * rs;
        s1.x = z1[4 * g + 0] * rs; s1.y = z1[4 * g + 1] * rs;
        s1.z = z1[4 * g + 2] * rs; s1.w = z1[4 * g + 3] * rs;
        *(float4*)&Srow[8 * g + 4 * hsel]      = s0;
        *(float4*)&Srow[8 * g + 4 * hsel + 32] = s1;
    }
}

// ---------------------------------------------------------------------------
// Kernel 2: pmask (unchanged)
// ---------------------------------------------------------------------------
__global__ __launch_bounds__(256) void k_pmask(const int* __restrict__ mask,
                                               float* __restrict__ pmask)
{
    __shared__ int s_any;
    if (threadIdx.x == 0) s_any = 0;
    __syncthreads();
    const int b = blockIdx.x;
    int any = 0;
    for (int i = threadIdx.x; i < Nn; i += blockDim.x)
        any |= (mask[(size_t)b * Nn + i] > 0) ? 1 : 0;
    if (any) atomicOr(&s_any, 1);
    __syncthreads();
    if (threadIdx.x < Kk)
        pmask[(size_t)b * Kk + threadIdx.x] = s_any ? 1.f : 0.f;
}

// ---------------------------------------------------------------------------
// Kernel 3a (v2): compact valid edges into dense (u|v<<15, w) triplets.
// Deterministic, no atomics. Removes 2 levels of pooled's load chain.
// ---------------------------------------------------------------------------
__global__ __launch_bounds__(256) void k_compact(
    const int* __restrict__ ei, const float* __restrict__ ew,
    const int* __restrict__ mask,
    int* __restrict__ uvp, float* __restrict__ eww, int* __restrict__ cnt)
{
    const int lane = threadIdx.x & 63;
    const int wid  = threadIdx.x >> 6;
    const int b    = blockIdx.x & 7;
    const int seg  = (blockIdx.x >> 3) * 4 + wid;   // 0..NSEG-1
    const int groupsPerBatch = Ee / 64;             // 5000
    const size_t eib = (size_t)b * 2 * Ee;
    const int* mb = mask + (size_t)b * Nn;
    const float* ewb = ew + (size_t)b * Ee;
    int*   uvs  = uvp + ((size_t)b * NSEG + seg) * SEGCAP;
    float* ewws = eww + ((size_t)b * NSEG + seg) * SEGCAP;

    int run = 0;
    for (int g = seg; g < groupsPerBatch; g += NSEG) {
        const int e0 = g * 64;
        const int u = ei[eib + e0 + lane];
        const int v = ei[eib + Ee + e0 + lane];
        const bool valid = (mb[u] > 0) && (mb[v] > 0);
        const unsigned long long mk = __ballot(valid);
        const int myoff = __popcll(mk & ((1ull << lane) - 1ull));
        if (valid) {
            uvs[run + myoff]  = u | (v << 15);      // u,v < 20000 < 2^15
            ewws[run + myoff] = ewb[e0 + lane];
        }
        run += (int)__popcll(mk);
    }
    if (lane == 0) cnt[b * NSEG + seg] = run;
}

// ---------------------------------------------------------------------------
// Kernel 3b (v5): pooled[b,k,l] = sum_e w_e * S[b,v_e,k] * S[b,u_e,l]
// Dense triplet stream -> 2-level chain only (uv load -> S gather).
// Phase-split per 16-edge chunk: issue all 8 uv/w loads, then the 32
// gathers, then cvt + 4 MFMA. Zero shfl / LDS / waitcnt in hot loop.
// ---------------------------------------------------------------------------
template<bool USE_PT>
__global__ __launch_bounds__(256) void k_pooled_edges(
    const float* __restrict__ S, const int* __restrict__ uvp,
    const float* __restrict__ eww, const int* __restrict__ cnt,
    float* __restrict__ out)  // pt or pooled
{
    __shared__ float tile[Kk * Kk];                 // 16 KB
    const int tid  = threadIdx.x;
    const int lane = tid & 63;
    const int wid  = tid >> 6;
    const int hsel = lane >> 5;
    const int m32  = lane & 31;

    for (int i = tid; i < Kk * Kk; i += 256) tile[i] = 0.f;
    __syncthreads();

    const int b   = blockIdx.x & 7;                 // XCD-pinned batch
    const int seg = (blockIdx.x >> 3) * 4 + wid;    // 0..NSEG-1
    const float* Sb = S + (size_t)b * Nn * Kk;
    const int*   uvs  = uvp + ((size_t)b * NSEG + seg) * SEGCAP;
    const float* ewws = eww + ((size_t)b * NSEG + seg) * SEGCAP;
    const int nc = cnt[b * NSEG + seg];

    f32x16 acc00 = 0.f, acc01 = 0.f, acc10 = 0.f, acc11 = 0.f;

    for (int c0 = 0; c0 < nc; c0 += 16) {
        // phase 1: 8 independent dense loads (half-wave-uniform broadcast)
        int uvj[8]; float wwj[8];
        #pragma unroll
        for (int j = 0; j < 8; ++j) {
            const int sidx = c0 + hsel * 8 + j;
            const bool ok = sidx < nc;
            uvj[j] = uvs[ok ? sidx : 0];
            wwj[j] = ok ? ewws[sidx] : 0.f;
        }
        // phase 2: 32 independent coalesced gathers + cvt
        bf16x8 a0, a1, b0, b1;
        #pragma unroll
        for (int j = 0; j < 8; ++j) {
            const int uu = uvj[j] & 32767;
            const int vv = (uvj[j] >> 15) & 32767;
            const float ww = wwj[j];
            const float sv0 = Sb[(size_t)vv * Kk + m32];
            const float sv1 = Sb[(size_t)vv * Kk + 32 + m32];
            const float su0 = Sb[(size_t)uu * Kk + m32];
            const float su1 = Sb[(size_t)uu * Kk + 32 + m32];
            a0[j] = (short)f2bf(ww * sv0);
            a1[j] = (short)f2bf(ww * sv1);
            b0[j] = (short)f2bf(su0);
            b1[j] = (short)f2bf(su1);
        }
        acc00 = __builtin_amdgcn_mfma_f32_32x32x16_bf16(a0, b0, acc00, 0, 0, 0);
        acc01 = __builtin_amdgcn_mfma_f32_32x32x16_bf16(a0, b1, acc01, 0, 0, 0);
        acc10 = __builtin_amdgcn_mfma_f32_32x32x16_bf16(a1, b0, acc10, 0, 0, 0);
        acc11 = __builtin_amdgcn_mfma_f32_32x32x16_bf16(a1, b1, acc11, 0, 0, 0);
    }

    // block-reduce 4 waves into LDS tile (verified 32x32 C/D mapping)
    const int rbase = 4 * (lane >> 5);
    const int col   = lane & 31;
    #pragma unroll
    for (int r = 0; r < 16; ++r) {
        const int row = (r & 3) + 8 * (r >> 2) + rbase;
        atomicAdd(&tile[row * Kk + col],              acc00[r]);
        atomicAdd(&tile[row * Kk + 32 + col],         acc01[r]);
        atomicAdd(&tile[(32 + row) * Kk + col],       acc10[r]);
        atomicAdd(&tile[(32 + row) * Kk + 32 + col],  acc11[r]);
    }
    __syncthreads();

    if (USE_PT) {
        float* pt = out + (size_t)blockIdx.x * (Kk * Kk);
        for (int i = tid; i < Kk * Kk; i += 256) pt[i] = tile[i];
    } else {
        float* pb = out + (size_t)b * Kk * Kk;
        for (int i = tid; i < Kk * Kk; i += 256) atomicAdd(&pb[i], tile[i]);
    }
}

// ---------------------------------------------------------------------------
// Kernel 3c (v2): sum 64 partial tiles per batch; coalesced, 64 blocks.
// ---------------------------------------------------------------------------
__global__ __launch_bounds__(256) void k_reduce_pooled(
    const float* __restrict__ pt, float* __restrict__ pooled)
{
    const int b    = blockIdx.x & 7;
    const int part = blockIdx.x >> 3;               // 0..7
    const int tid  = threadIdx.x;
    #pragma unroll
    for (int i2 = 0; i2 < 2; ++i2) {
        const int i = part * 512 + i2 * 256 + tid;
        float s = 0.f;
        #pragma unroll 8
        for (int slot = 0; slot < 64; ++slot)
            s += pt[(size_t)(slot * 8 + b) * (Kk * Kk) + i];
        pooled[(size_t)b * Kk * Kk + i] = s;
    }
}

// ---------------------------------------------------------------------------
// Kernel 4: pfeat (MFMA, unchanged from R5)
// ---------------------------------------------------------------------------
__global__ __launch_bounds__(256) void k_pfeat(
    const float* __restrict__ x, const float* __restrict__ S,
    float* __restrict__ pfeat)
{
    const int tid  = threadIdx.x;
    const int lane = tid & 63;
    const int wid  = tid >> 6;
    const int b    = blockIdx.x & 7;
    const int slot = blockIdx.x >> 3;
    const int bpb  = gridDim.x >> 3;

    const float* xb  = x + (size_t)b * Nn * Cc;
    const float* Sbp = S + (size_t)b * Nn * Kk;

    const int nodeoff = (lane >> 5) * 8;
    const int kc      = lane & 31;
    const int c       = wid * 32 + kc;

    f32x16 acc0 = 0.f, acc1 = 0.f;

    const int chunks = Nn / 16;
    for (int ch = slot; ch < chunks; ch += bpb) {
        const int nb = ch * 16 + nodeoff;
        float a0f[8], a1f[8], bff[8];
        #pragma unroll
        for (int j = 0; j < 8; ++j) {
            const size_t n = (size_t)(nb + j);
            a0f[j] = Sbp[n * Kk + kc];
            a1f[j] = Sbp[n * Kk + 32 + kc];
            bff[j] = xb[n * Cc + c];
        }
        bf16x8 a0, a1, bbf;
        #pragma unroll
        for (int j = 0; j < 8; ++j) {
            a0[j]  = (short)f2bf(a0f[j]);
            a1[j]  = (short)f2bf(a1f[j]);
            bbf[j] = (short)f2bf(bff[j]);
        }
        acc0 = __builtin_amdgcn_mfma_f32_32x32x16_bf16(a0, bbf, acc0, 0, 0, 0);
        acc1 = __builtin_amdgcn_mfma_f32_32x32x16_bf16(a1, bbf, acc1, 0, 0, 0);
    }

    float* pf = pfeat + (size_t)b * Kk * Cc;
    const int colc  = wid * 32 + (lane & 31);
    const int rbase = 4 * (lane >> 5);
    #pragma unroll
    for (int r = 0; r < 16; ++r) {
        const int row = (r & 3) + 8 * (r >> 2) + rbase;
        atomicAdd(&pf[row * Cc + colc],        acc0[r]);
        atomicAdd(&pf[(32 + row) * Cc + colc], acc1[r]);
    }
}

// ---------------------------------------------------------------------------
extern "C" void kernel_launch(void* const* d_in, const int* in_sizes, int n_in,
                              void* d_out, int out_size, void* d_ws, size_t ws_size,
                              hipStream_t stream)
{
    const float* x    = (const float*)d_in[0];
    const int*   ei   = (const int*)d_in[1];     // int64 ref -> int32 on device
    const float* ew   = (const float*)d_in[2];
    const int*   mask = (const int*)d_in[3];
    const float* W1   = (const float*)d_in[4];
    const float* b1   = (const float*)d_in[5];
    const float* W2   = (const float*)d_in[6];
    const float* b2   = (const float*)d_in[7];

    float* out    = (float*)d_out;
    float* pfeat  = out;
    float* pooled = out + (size_t)Bb * Kk * Cc;
    float* pmask  = out + (size_t)Bb * Kk * Cc + (size_t)Bb * Kk * Kk;

    // workspace layout
    float* S    = (float*)d_ws;                                 // 40.96 MB
    int*   uvp  = (int*)(S + (size_t)Bb * Nn * Kk);             // 10.49 MB
    float* eww  = (float*)(uvp + (size_t)Bb * NSEG * SEGCAP);   // 10.49 MB
    int*   cnt  = (int*)(eww + (size_t)Bb * NSEG * SEGCAP);     // 8 KB
    float* pt   = (float*)(cnt + Bb * NSEG);                    // 8.39 MB
    const size_t needed = (size_t)((char*)(pt + (size_t)512 * Kk * Kk) - (char*)d_ws);
    const bool use_pt = ws_size >= needed;

    hipMemsetAsync(d_out, 0, sizeof(float) * (size_t)out_size, stream);

    k_compute_S<<<1250, 256, 0, stream>>>(x, mask, W1, b1, W2, b2, S);
    k_pmask<<<Bb, 256, 0, stream>>>(mask, pmask);
    k_compact<<<512, 256, 0, stream>>>(ei, ew, mask, uvp, eww, cnt);
    if (use_pt) {
        k_pooled_edges<true><<<512, 256, 0, stream>>>(S, uvp, eww, cnt, pt);
        k_reduce_pooled<<<64, 256, 0, stream>>>(pt, pooled);
    } else {
        k_pooled_edges<false><<<512, 256, 0, stream>>>(S, uvp, eww, cnt, pooled);
    }
    k_pfeat<<<512, 256, 0, stream>>>(x, S, pfeat);
}